// Round 6
// baseline (182.371 us; speedup 1.0000x reference)
//
#include <hip/hip_runtime.h>
#include <hip/hip_bf16.h>
#include <math.h>

#define B_  16
#define N_  8192
#define D_  128
#define H_  64
#define E_  64
#define EPSLN 1e-5f

typedef __attribute__((ext_vector_type(8))) short short8;
typedef __attribute__((ext_vector_type(4))) float f32x4;

// workspace layout (bytes):
//   partials : 512*128 f32   @ 0        (262144)  [b*32+bx][d]
//   ctr      : 16 int        @ 262144   (64)
//   Wrt      : H*D bf16      @ 262208   (16384)   Wrt[h][d] = ln_w[d]*Wr[d,h]
//   ug       : H f32         @ 278592   (256)     u[h] = ln_w @ Wr
//   qg       : H f32         @ 278848   (256)     q[h] = ln_b @ Wr
//   W2t      : B*E*H bf16    @ 279104   (131072)  W2t[b][e][h] = ml[h]*Wo[h,e]
//   C2g      : B*E f32       @ 410176   (4096)
//   Zg       : B*N*H bf16    @ 1048576  (16777216)
#define WSB_PART 0
#define WSB_CTR  262144
#define WSB_WRT  262208
#define WSB_U    278592
#define WSB_Q    278848
#define WSB_W2T  279104
#define WSB_C2   410176
#define WSB_Z    1048576

static __device__ __forceinline__ unsigned short f2bf(float f) {
    union { float f; unsigned u; } c; c.f = f;
    unsigned u = c.u;
    return (unsigned short)((u + 0x7FFFu + ((u >> 16) & 1u)) >> 16);  // RNE
}
static __device__ __forceinline__ float bf2f(short v) {
    union { unsigned u; float f; } c;
    c.u = ((unsigned)(unsigned short)v) << 16;
    return c.f;
}

// ---------------------------------------------------------------------------
// k_prep (1 block): Wrt (bf16 transposed, ln_w-folded), u, q; zero ctr.
// ---------------------------------------------------------------------------
__global__ __launch_bounds__(256) void k_prep(const float* __restrict__ ln_w,
                                              const float* __restrict__ ln_b,
                                              const float* __restrict__ Wr,
                                              unsigned short* __restrict__ Wrt,
                                              float* __restrict__ ug,
                                              float* __restrict__ qg,
                                              int* __restrict__ ctr) {
    __shared__ float ru[4][H_], rq[4][H_];
    int t = threadIdx.x;
    if (t < 16) ctr[t] = 0;
    int h = t & 63, dq = t >> 6;
    float u = 0.f, q = 0.f;
    for (int i = 0; i < 32; ++i) {
        int d = dq * 32 + i;
        float wr = Wr[d * H_ + h];          // coalesced across h
        float lw = ln_w[d];
        u += lw * wr;
        q += ln_b[d] * wr;
        Wrt[h * D_ + d] = f2bf(lw * wr);
    }
    ru[dq][h] = u; rq[dq][h] = q;
    __syncthreads();
    if (t < H_) {
        ug[t] = ru[0][t] + ru[1][t] + ru[2][t] + ru[3][t];
        qg[t] = rq[0][t] + rq[1][t] + rq[2][t] + rq[3][t];
    }
}

// ---------------------------------------------------------------------------
// k_pass1: per 256-row tile —
//   COALESCED staging x -> LDS bf16 (XOR-swizzled 16B granules); row stats
//   via 16-lane shfl reduction in fp32 (each 16-lane group holds one row);
//   weighted colsum partials; MFMA Zraw = (x .* ln_w) @ Wr;
//   Z = rs*Zraw - rs*mu*u + q -> bf16 global.
//   Last block per batch (device-scope ctr) reduces partials -> W2t, C2.
// ---------------------------------------------------------------------------
__global__ __launch_bounds__(256, 2) void k_pass1(const float* __restrict__ x,
                                                  const unsigned short* __restrict__ Wrt,
                                                  const float* __restrict__ ug,
                                                  const float* __restrict__ qg,
                                                  const float* __restrict__ ln_w,
                                                  const float* __restrict__ ln_b,
                                                  const float* __restrict__ Wl,
                                                  const float* __restrict__ bl,
                                                  const float* __restrict__ br,
                                                  const float* __restrict__ Wo,
                                                  const float* __restrict__ bo,
                                                  float* __restrict__ partials,
                                                  int* __restrict__ ctr,
                                                  unsigned short* __restrict__ W2t,
                                                  float* __restrict__ C2g,
                                                  unsigned short* __restrict__ Zg) {
    __shared__ short xs[256 * 128];            // 64 KB
    __shared__ float mul[256], rsl[256];       // 2 KB
    __shared__ float redc[4][128];             // 2 KB (colsum; reused by combine)
    __shared__ float ush[H_], qsh[H_];         // 512 B
    __shared__ int   isl;

    int b = blockIdx.y, bx = blockIdx.x, t = threadIdx.x;
    int rowbase = bx * 256;

    if (t < H_) { ush[t] = ug[t]; qsh[t] = qg[t]; }

    // ---- coalesced staging + fp32 row stats via 16-lane shuffle ----
    {
        size_t tb4 = (size_t)(b * N_ + rowbase) * 32;   // tile base, float4 units
        const float4* x4 = (const float4*)x;
#pragma unroll
        for (int k = 0; k < 16; ++k) {
            int idx = t + 256 * k;                       // wave: 2KB contiguous
            int row = idx >> 4, g = idx & 15;
            float4 va = x4[tb4 + 2 * idx];
            float4 vb = x4[tb4 + 2 * idx + 1];
            float s  = (va.x + va.y) + (va.z + va.w) + (vb.x + vb.y) + (vb.z + vb.w);
            float s2 = (va.x * va.x + va.y * va.y) + (va.z * va.z + va.w * va.w)
                     + (vb.x * vb.x + vb.y * vb.y) + (vb.z * vb.z + vb.w * vb.w);
            // 16 lanes of this group hold granules 0..15 of the same row
            s  += __shfl_xor(s, 1, 16);  s2 += __shfl_xor(s2, 1, 16);
            s  += __shfl_xor(s, 2, 16);  s2 += __shfl_xor(s2, 2, 16);
            s  += __shfl_xor(s, 4, 16);  s2 += __shfl_xor(s2, 4, 16);
            s  += __shfl_xor(s, 8, 16);  s2 += __shfl_xor(s2, 8, 16);
            union { short8 s8; __hip_bfloat162 h2[4]; } u;
            u.h2[0] = __float22bfloat162_rn(make_float2(va.x, va.y));
            u.h2[1] = __float22bfloat162_rn(make_float2(va.z, va.w));
            u.h2[2] = __float22bfloat162_rn(make_float2(vb.x, vb.y));
            u.h2[3] = __float22bfloat162_rn(make_float2(vb.z, vb.w));
            *(short8*)&xs[row * 128 + ((g ^ (row & 15)) * 8)] = u.s8;
            if ((t & 15) == 0) {
                float mu  = s * (1.f / D_);
                float var = s2 * (1.f / D_) - mu * mu;
                mul[row] = mu;
                rsl[row] = rsqrtf(var + EPSLN);
            }
        }
    }
    __syncthreads();

    // ---- weighted colsum partials from the bf16 tile ----
    {
        int cp = (t & 63) * 2, q = t >> 6;      // q = wave -> row uniform in wave
        int g = cp >> 3, jo = cp & 7;
        float a0 = 0.f, a1 = 0.f;
#pragma unroll 8
        for (int i = 0; i < 64; ++i) {
            int r = q * 64 + i;
            short2 v = *(const short2*)&xs[r * 128 + ((g ^ (r & 15)) * 8) + jo];
            float w = rsl[r], m = mul[r];
            a0 += w * (bf2f(v.x) - m);
            a1 += w * (bf2f(v.y) - m);
        }
        redc[q][cp] = a0;
        redc[q][cp + 1] = a1;
    }
    __syncthreads();
    if (t < 128) {
        float s = redc[0][t] + redc[1][t] + redc[2][t] + redc[3][t];
        partials[(size_t)(b * 32 + bx) * D_ + t] = s;
    }
    __syncthreads();                            // partials drained to L2
    if (t == 0) {
        __threadfence();                        // device-visible (release)
        int old = atomicAdd(&ctr[b], 1);
        isl = (old == 31);
    }

    // ---- MFMA: Zraw = xs @ Wrt^T  (256x64, K=128) ----
    int wv = t >> 6, lane = t & 63;
    int m16 = lane & 15, quad = lane >> 4;

    f32x4 acc[4][4];
#pragma unroll
    for (int i = 0; i < 4; ++i)
#pragma unroll
        for (int j = 0; j < 4; ++j) acc[i][j] = (f32x4){0.f, 0.f, 0.f, 0.f};

#pragma unroll
    for (int kc = 0; kc < 4; ++kc) {
        short8 af[4], bf[4];
#pragma unroll
        for (int mt = 0; mt < 4; ++mt) {
            int row = wv * 64 + mt * 16 + m16;
            int g = kc * 4 + quad;
            af[mt] = *(const short8*)&xs[row * 128 + ((g ^ m16) * 8)];
        }
#pragma unroll
        for (int nt = 0; nt < 4; ++nt) {
            bf[nt] = *(const short8*)(Wrt + (size_t)(nt * 16 + m16) * D_ + kc * 32 + quad * 8);
        }
#pragma unroll
        for (int mt = 0; mt < 4; ++mt)
#pragma unroll
            for (int nt = 0; nt < 4; ++nt)
                acc[mt][nt] = __builtin_amdgcn_mfma_f32_16x16x32_bf16(
                    af[mt], bf[nt], acc[mt][nt], 0, 0, 0);
    }

    // ---- epilogue: Z = rs*Zraw - rs*mu*u + q -> bf16 ----
    size_t zbase = (size_t)(b * N_ + rowbase) * H_;
#pragma unroll
    for (int mt = 0; mt < 4; ++mt) {
        int rb = wv * 64 + mt * 16 + quad * 4;
        float mu0 = mul[rb + 0], rs0 = rsl[rb + 0];
        float mu1 = mul[rb + 1], rs1 = rsl[rb + 1];
        float mu2 = mul[rb + 2], rs2 = rsl[rb + 2];
        float mu3 = mul[rb + 3], rs3 = rsl[rb + 3];
#pragma unroll
        for (int nt = 0; nt < 4; ++nt) {
            int col = nt * 16 + m16;
            float uc = ush[col], qc = qsh[col];
            unsigned short* zp = Zg + zbase + (size_t)rb * H_ + col;
            zp[0 * H_] = f2bf(rs0 * (acc[mt][nt][0] - mu0 * uc) + qc);
            zp[1 * H_] = f2bf(rs1 * (acc[mt][nt][1] - mu1 * uc) + qc);
            zp[2 * H_] = f2bf(rs2 * (acc[mt][nt][2] - mu2 * uc) + qc);
            zp[3 * H_] = f2bf(rs3 * (acc[mt][nt][3] - mu3 * uc) + qc);
        }
    }

    // ---- last block for this batch: combine -> W2t, C2 ----
    __syncthreads();
    if (!isl) return;
    __threadfence();                            // acquire

    float* cm   = &redc[0][0];                  // 128
    float* mlh  = &redc[1][0];                  // 64
    float* redC = &redc[2][0];                  // 4 x 64

    if (t < D_) {
        float s = 0.f;
#pragma unroll 8
        for (int k = 0; k < 32; ++k)
            s += partials[(size_t)(b * 32 + k) * D_ + t];
        cm[t] = ln_w[t] * s * (1.f / N_) + ln_b[t];
    }
    __syncthreads();
    if (t < H_) {
        float a = bl[t];
        for (int d = 0; d < D_; ++d) a += cm[d] * Wl[d * H_ + t];
        mlh[t] = a;
    }
    __syncthreads();

    int e = t & 63, hq = t >> 6;
    float cpart = 0.f;
    size_t wb = (size_t)b * E_ * H_;
    for (int i = 0; i < 16; ++i) {
        int h = hq * 16 + i;
        float wo = Wo[h * E_ + e];              // coalesced across e
        float w2 = mlh[h] * wo;
        cpart += w2 * br[h];
        W2t[wb + (size_t)e * H_ + h] = f2bf(w2);
    }
    redC[hq * 64 + e] = cpart;
    __syncthreads();
    if (t < E_)
        C2g[b * E_ + t] = redC[0 * 64 + t] + redC[1 * 64 + t]
                        + redC[2 * 64 + t] + redC[3 * 64 + t] + bo[t];
}

// ---------------------------------------------------------------------------
// k_pass2: out = Z @ W2 + C2.  Pure MFMA GEMM (256x64, K=64), no LDS tile —
// A-frags straight from Zg (64B-contiguous per wave), B-frags from W2t (L1).
// ---------------------------------------------------------------------------
__global__ __launch_bounds__(256) void k_pass2(const unsigned short* __restrict__ Zg,
                                               const unsigned short* __restrict__ W2t,
                                               const float* __restrict__ C2g,
                                               float* __restrict__ out) {
    __shared__ float C2l[E_];
    int b = blockIdx.y, bx = blockIdx.x, t = threadIdx.x;
    int rowbase = bx * 256;
    if (t < E_) C2l[t] = C2g[b * E_ + t];
    __syncthreads();

    int wv = t >> 6, lane = t & 63;
    int m16 = lane & 15, quad = lane >> 4;

    f32x4 acc[4][4];
#pragma unroll
    for (int i = 0; i < 4; ++i)
#pragma unroll
        for (int j = 0; j < 4; ++j) acc[i][j] = (f32x4){0.f, 0.f, 0.f, 0.f};

    size_t zbase = (size_t)(b * N_ + rowbase) * H_;
    const unsigned short* Wb = W2t + (size_t)b * E_ * H_;

#pragma unroll
    for (int kc = 0; kc < 2; ++kc) {
        short8 af[4], bf[4];
#pragma unroll
        for (int mt = 0; mt < 4; ++mt) {
            int row = wv * 64 + mt * 16 + m16;
            af[mt] = *(const short8*)(Zg + zbase + (size_t)row * H_ + kc * 32 + quad * 8);
        }
#pragma unroll
        for (int nt = 0; nt < 4; ++nt) {
            bf[nt] = *(const short8*)(Wb + (size_t)(nt * 16 + m16) * H_ + kc * 32 + quad * 8);
        }
#pragma unroll
        for (int mt = 0; mt < 4; ++mt)
#pragma unroll
            for (int nt = 0; nt < 4; ++nt)
                acc[mt][nt] = __builtin_amdgcn_mfma_f32_16x16x32_bf16(
                    af[mt], bf[nt], acc[mt][nt], 0, 0, 0);
    }

    size_t outbase = (size_t)(b * N_ + rowbase) * E_;
#pragma unroll
    for (int mt = 0; mt < 4; ++mt) {
        int rb = wv * 64 + mt * 16 + quad * 4;
#pragma unroll
        for (int nt = 0; nt < 4; ++nt) {
            int col = nt * 16 + m16;
            float Cc = C2l[col];
            float* o = out + outbase + (size_t)rb * E_ + col;
            o[0 * E_] = acc[mt][nt][0] + Cc;
            o[1 * E_] = acc[mt][nt][1] + Cc;
            o[2 * E_] = acc[mt][nt][2] + Cc;
            o[3 * E_] = acc[mt][nt][3] + Cc;
        }
    }
}

extern "C" void kernel_launch(void* const* d_in, const int* in_sizes, int n_in,
                              void* d_out, int out_size, void* d_ws, size_t ws_size,
                              hipStream_t stream) {
    const float* x    = (const float*)d_in[0];
    const float* ln_w = (const float*)d_in[1];
    const float* ln_b = (const float*)d_in[2];
    const float* Wl   = (const float*)d_in[3];
    const float* bl   = (const float*)d_in[4];
    const float* Wr   = (const float*)d_in[5];
    const float* br   = (const float*)d_in[6];
    const float* Wo   = (const float*)d_in[7];
    const float* bo   = (const float*)d_in[8];
    float* out = (float*)d_out;
    char* ws   = (char*)d_ws;

    float*          partials = (float*)(ws + WSB_PART);
    int*            ctr      = (int*)(ws + WSB_CTR);
    unsigned short* Wrt      = (unsigned short*)(ws + WSB_WRT);
    float*          ug       = (float*)(ws + WSB_U);
    float*          qg       = (float*)(ws + WSB_Q);
    unsigned short* W2t      = (unsigned short*)(ws + WSB_W2T);
    float*          C2g      = (float*)(ws + WSB_C2);
    unsigned short* Zg       = (unsigned short*)(ws + WSB_Z);

    k_prep<<<1, 256, 0, stream>>>(ln_w, ln_b, Wr, Wrt, ug, qg, ctr);
    k_pass1<<<dim3(32, B_), 256, 0, stream>>>(x, Wrt, ug, qg, ln_w, ln_b, Wl,
                                              bl, br, Wo, bo, partials, ctr,
                                              W2t, C2g, Zg);
    k_pass2<<<dim3(32, B_), 256, 0, stream>>>(Zg, W2t, C2g, out);
}

// Round 7
// 167.159 us; speedup vs baseline: 1.0910x; 1.0910x over previous
//
#include <hip/hip_runtime.h>
#include <hip/hip_bf16.h>
#include <math.h>

#define B_  16
#define N_  8192
#define D_  128
#define H_  64
#define E_  64
#define EPSLN 1e-5f

typedef __attribute__((ext_vector_type(8))) short short8;
typedef __attribute__((ext_vector_type(4))) float f32x4;

// workspace layout (bytes):
//   partials : 512*128 f32   @ 0        (262144)  [b*32+bx][d]
//   ctr      : 16 int        @ 262144   (64)
//   Wrt      : H*D bf16      @ 262208   (16384)   Wrt[h][d] = ln_w[d]*Wr[d,h]
//   ug       : H f32         @ 278592   (256)     u[h] = ln_w @ Wr
//   qg       : H f32         @ 278848   (256)     q[h] = ln_b @ Wr
//   W2t      : B*E*H bf16    @ 279104   (131072)  W2t[b][e][h] = ml[h]*Wo[h,e]
//   C2g      : B*E f32       @ 410176   (4096)
//   Zg       : B*N*H bf16    @ 1048576  (16777216)
#define WSB_PART 0
#define WSB_CTR  262144
#define WSB_WRT  262208
#define WSB_U    278592
#define WSB_Q    278848
#define WSB_W2T  279104
#define WSB_C2   410176
#define WSB_Z    1048576

static __device__ __forceinline__ unsigned short f2bf(float f) {
    union { float f; unsigned u; } c; c.f = f;
    unsigned u = c.u;
    return (unsigned short)((u + 0x7FFFu + ((u >> 16) & 1u)) >> 16);  // RNE
}
static __device__ __forceinline__ float bf2f(short v) {
    union { unsigned u; float f; } c;
    c.u = ((unsigned)(unsigned short)v) << 16;
    return c.f;
}

// ---------------------------------------------------------------------------
// k_prep (1 block): Wrt (bf16 transposed, ln_w-folded), u, q; zero ctr.
// ---------------------------------------------------------------------------
__global__ __launch_bounds__(256) void k_prep(const float* __restrict__ ln_w,
                                              const float* __restrict__ ln_b,
                                              const float* __restrict__ Wr,
                                              unsigned short* __restrict__ Wrt,
                                              float* __restrict__ ug,
                                              float* __restrict__ qg,
                                              int* __restrict__ ctr) {
    __shared__ float ru[4][H_], rq[4][H_];
    int t = threadIdx.x;
    if (t < 16) ctr[t] = 0;
    int h = t & 63, dq = t >> 6;
    float u = 0.f, q = 0.f;
    for (int i = 0; i < 32; ++i) {
        int d = dq * 32 + i;
        float wr = Wr[d * H_ + h];          // coalesced across h
        float lw = ln_w[d];
        u += lw * wr;
        q += ln_b[d] * wr;
        Wrt[h * D_ + d] = f2bf(lw * wr);
    }
    ru[dq][h] = u; rq[dq][h] = q;
    __syncthreads();
    if (t < H_) {
        ug[t] = ru[0][t] + ru[1][t] + ru[2][t] + ru[3][t];
        qg[t] = rq[0][t] + rq[1][t] + rq[2][t] + rq[3][t];
    }
}

// ---------------------------------------------------------------------------
// k_pass1: per 256-row tile —
//   1) COALESCED staging x -> LDS bf16 (XOR-swizzled 16B granules); one
//      float4 per thread per iter, NO cross-lane ops in the loop.
//   2) row stats from the bf16 LDS tile (thread t = row t; granule order
//      rotated by lane>>4 -> conflict-free b128 reads).
//   3) weighted colsum partials; MFMA Zraw = (x .* ln_w) @ Wr;
//      Z = rs*Zraw - rs*mu*u + q -> bf16 global.
//   Last block per batch (device-scope ctr) reduces partials -> W2t, C2.
// ---------------------------------------------------------------------------
__global__ __launch_bounds__(256, 2) void k_pass1(const float* __restrict__ x,
                                                  const unsigned short* __restrict__ Wrt,
                                                  const float* __restrict__ ug,
                                                  const float* __restrict__ qg,
                                                  const float* __restrict__ ln_w,
                                                  const float* __restrict__ ln_b,
                                                  const float* __restrict__ Wl,
                                                  const float* __restrict__ bl,
                                                  const float* __restrict__ br,
                                                  const float* __restrict__ Wo,
                                                  const float* __restrict__ bo,
                                                  float* __restrict__ partials,
                                                  int* __restrict__ ctr,
                                                  unsigned short* __restrict__ W2t,
                                                  float* __restrict__ C2g,
                                                  unsigned short* __restrict__ Zg) {
    __shared__ short xs[256 * 128];            // 64 KB
    __shared__ float mul[256], rsl[256];       // 2 KB
    __shared__ float redc[4][128];             // 2 KB (colsum; reused by combine)
    __shared__ float ush[H_], qsh[H_];         // 512 B
    __shared__ int   isl;

    int b = blockIdx.y, bx = blockIdx.x, t = threadIdx.x;
    int rowbase = bx * 256;
    int lane = t & 63;

    if (t < H_) { ush[t] = ug[t]; qsh[t] = qg[t]; }

    // ---- 1) coalesced staging: one float4/thread/iter, no dependencies ----
    {
        size_t tb4 = (size_t)(b * N_ + rowbase) * 32;   // tile base, float4 units
        const float4* x4 = (const float4*)x;
#pragma unroll 8
        for (int k = 0; k < 32; ++k) {
            int idx = t + 256 * k;                       // wave: 1KB contiguous
            int row = idx >> 5, c4 = idx & 31;           // c4-th float4 of row
            float4 v = x4[tb4 + idx];
            union { unsigned u[2]; __hip_bfloat162 h2[2]; } cv;
            cv.h2[0] = __float22bfloat162_rn(make_float2(v.x, v.y));
            cv.h2[1] = __float22bfloat162_rn(make_float2(v.z, v.w));
            int g = c4 >> 1, half = c4 & 1;              // 16B granule, 8B half
            *(uint2*)&xs[row * 128 + ((g ^ (row & 15)) * 8) + half * 4] =
                *(uint2*)cv.u;
        }
    }
    __syncthreads();

    // ---- 2) row stats from bf16 tile (thread t = row t) ----
    {
        int sw = t & 15, rot = lane >> 4;                // rot breaks 4-way banks
        float s = 0.f, s2 = 0.f;
#pragma unroll
        for (int gi = 0; gi < 16; ++gi) {
            int g = (gi + rot) & 15;
            short8 v = *(const short8*)&xs[t * 128 + ((g ^ sw) * 8)];
#pragma unroll
            for (int j = 0; j < 8; ++j) {
                float f = bf2f(v[j]);
                s += f; s2 += f * f;
            }
        }
        float mu  = s * (1.f / D_);
        float var = s2 * (1.f / D_) - mu * mu;
        mul[t] = mu;
        rsl[t] = rsqrtf(var + EPSLN);
    }
    __syncthreads();

    // ---- 3) weighted colsum partials from the bf16 tile ----
    {
        int cp = (t & 63) * 2, q = t >> 6;      // q = wave -> row uniform in wave
        int g = cp >> 3, jo = cp & 7;
        float a0 = 0.f, a1 = 0.f;
#pragma unroll 8
        for (int i = 0; i < 64; ++i) {
            int r = q * 64 + i;
            short2 v = *(const short2*)&xs[r * 128 + ((g ^ (r & 15)) * 8) + jo];
            float w = rsl[r], m = mul[r];
            a0 += w * (bf2f(v.x) - m);
            a1 += w * (bf2f(v.y) - m);
        }
        redc[q][cp] = a0;
        redc[q][cp + 1] = a1;
    }
    __syncthreads();
    if (t < 128) {
        float s = redc[0][t] + redc[1][t] + redc[2][t] + redc[3][t];
        partials[(size_t)(b * 32 + bx) * D_ + t] = s;
    }
    __syncthreads();                            // partials drained
    if (t == 0) {
        __threadfence();                        // device-visible (release)
        int old = atomicAdd(&ctr[b], 1);
        isl = (old == 31);
    }

    // ---- MFMA: Zraw = xs @ Wrt^T  (256x64, K=128) ----
    int wv = t >> 6;
    int m16 = lane & 15, quad = lane >> 4;

    f32x4 acc[4][4];
#pragma unroll
    for (int i = 0; i < 4; ++i)
#pragma unroll
        for (int j = 0; j < 4; ++j) acc[i][j] = (f32x4){0.f, 0.f, 0.f, 0.f};

#pragma unroll
    for (int kc = 0; kc < 4; ++kc) {
        short8 af[4], bf[4];
#pragma unroll
        for (int mt = 0; mt < 4; ++mt) {
            int row = wv * 64 + mt * 16 + m16;
            int g = kc * 4 + quad;
            af[mt] = *(const short8*)&xs[row * 128 + ((g ^ m16) * 8)];
        }
#pragma unroll
        for (int nt = 0; nt < 4; ++nt) {
            bf[nt] = *(const short8*)(Wrt + (size_t)(nt * 16 + m16) * D_ + kc * 32 + quad * 8);
        }
#pragma unroll
        for (int mt = 0; mt < 4; ++mt)
#pragma unroll
            for (int nt = 0; nt < 4; ++nt)
                acc[mt][nt] = __builtin_amdgcn_mfma_f32_16x16x32_bf16(
                    af[mt], bf[nt], acc[mt][nt], 0, 0, 0);
    }

    // ---- epilogue: Z = rs*Zraw - rs*mu*u + q -> bf16 ----
    size_t zbase = (size_t)(b * N_ + rowbase) * H_;
#pragma unroll
    for (int mt = 0; mt < 4; ++mt) {
        int rb = wv * 64 + mt * 16 + quad * 4;
        float mu0 = mul[rb + 0], rs0 = rsl[rb + 0];
        float mu1 = mul[rb + 1], rs1 = rsl[rb + 1];
        float mu2 = mul[rb + 2], rs2 = rsl[rb + 2];
        float mu3 = mul[rb + 3], rs3 = rsl[rb + 3];
#pragma unroll
        for (int nt = 0; nt < 4; ++nt) {
            int col = nt * 16 + m16;
            float uc = ush[col], qc = qsh[col];
            unsigned short* zp = Zg + zbase + (size_t)rb * H_ + col;
            zp[0 * H_] = f2bf(rs0 * (acc[mt][nt][0] - mu0 * uc) + qc);
            zp[1 * H_] = f2bf(rs1 * (acc[mt][nt][1] - mu1 * uc) + qc);
            zp[2 * H_] = f2bf(rs2 * (acc[mt][nt][2] - mu2 * uc) + qc);
            zp[3 * H_] = f2bf(rs3 * (acc[mt][nt][3] - mu3 * uc) + qc);
        }
    }

    // ---- last block for this batch: combine -> W2t, C2 ----
    __syncthreads();
    if (!isl) return;
    __threadfence();                            // acquire

    float* cm   = &redc[0][0];                  // 128
    float* mlh  = &redc[1][0];                  // 64
    float* redC = &redc[2][0];                  // 4 x 64

    if (t < D_) {
        float s = 0.f;
#pragma unroll 8
        for (int k = 0; k < 32; ++k)
            s += partials[(size_t)(b * 32 + k) * D_ + t];
        cm[t] = ln_w[t] * s * (1.f / N_) + ln_b[t];
    }
    __syncthreads();
    if (t < H_) {
        float a = bl[t];
        for (int d = 0; d < D_; ++d) a += cm[d] * Wl[d * H_ + t];
        mlh[t] = a;
    }
    __syncthreads();

    int e = t & 63, hq = t >> 6;
    float cpart = 0.f;
    size_t wb = (size_t)b * E_ * H_;
    for (int i = 0; i < 16; ++i) {
        int h = hq * 16 + i;
        float wo = Wo[h * E_ + e];              // coalesced across e
        float w2 = mlh[h] * wo;
        cpart += w2 * br[h];
        W2t[wb + (size_t)e * H_ + h] = f2bf(w2);
    }
    redC[hq * 64 + e] = cpart;
    __syncthreads();
    if (t < E_)
        C2g[b * E_ + t] = redC[0 * 64 + t] + redC[1 * 64 + t]
                        + redC[2 * 64 + t] + redC[3 * 64 + t] + bo[t];
}

// ---------------------------------------------------------------------------
// k_pass2: out = Z @ W2 + C2.  Pure MFMA GEMM (256x64, K=64), no LDS tile —
// A-frags straight from Zg (64B-contiguous per wave), B-frags from W2t (L1).
// ---------------------------------------------------------------------------
__global__ __launch_bounds__(256) void k_pass2(const unsigned short* __restrict__ Zg,
                                               const unsigned short* __restrict__ W2t,
                                               const float* __restrict__ C2g,
                                               float* __restrict__ out) {
    __shared__ float C2l[E_];
    int b = blockIdx.y, bx = blockIdx.x, t = threadIdx.x;
    int rowbase = bx * 256;
    if (t < E_) C2l[t] = C2g[b * E_ + t];
    __syncthreads();

    int wv = t >> 6, lane = t & 63;
    int m16 = lane & 15, quad = lane >> 4;

    f32x4 acc[4][4];
#pragma unroll
    for (int i = 0; i < 4; ++i)
#pragma unroll
        for (int j = 0; j < 4; ++j) acc[i][j] = (f32x4){0.f, 0.f, 0.f, 0.f};

    size_t zbase = (size_t)(b * N_ + rowbase) * H_;
    const unsigned short* Wb = W2t + (size_t)b * E_ * H_;

#pragma unroll
    for (int kc = 0; kc < 2; ++kc) {
        short8 af[4], bf[4];
#pragma unroll
        for (int mt = 0; mt < 4; ++mt) {
            int row = wv * 64 + mt * 16 + m16;
            af[mt] = *(const short8*)(Zg + zbase + (size_t)row * H_ + kc * 32 + quad * 8);
        }
#pragma unroll
        for (int nt = 0; nt < 4; ++nt) {
            bf[nt] = *(const short8*)(Wb + (size_t)(nt * 16 + m16) * H_ + kc * 32 + quad * 8);
        }
#pragma unroll
        for (int mt = 0; mt < 4; ++mt)
#pragma unroll
            for (int nt = 0; nt < 4; ++nt)
                acc[mt][nt] = __builtin_amdgcn_mfma_f32_16x16x32_bf16(
                    af[mt], bf[nt], acc[mt][nt], 0, 0, 0);
    }

    size_t outbase = (size_t)(b * N_ + rowbase) * E_;
#pragma unroll
    for (int mt = 0; mt < 4; ++mt) {
        int rb = wv * 64 + mt * 16 + quad * 4;
#pragma unroll
        for (int nt = 0; nt < 4; ++nt) {
            int col = nt * 16 + m16;
            float Cc = C2l[col];
            float* o = out + outbase + (size_t)rb * E_ + col;
            o[0 * E_] = acc[mt][nt][0] + Cc;
            o[1 * E_] = acc[mt][nt][1] + Cc;
            o[2 * E_] = acc[mt][nt][2] + Cc;
            o[3 * E_] = acc[mt][nt][3] + Cc;
        }
    }
}

extern "C" void kernel_launch(void* const* d_in, const int* in_sizes, int n_in,
                              void* d_out, int out_size, void* d_ws, size_t ws_size,
                              hipStream_t stream) {
    const float* x    = (const float*)d_in[0];
    const float* ln_w = (const float*)d_in[1];
    const float* ln_b = (const float*)d_in[2];
    const float* Wl   = (const float*)d_in[3];
    const float* bl   = (const float*)d_in[4];
    const float* Wr   = (const float*)d_in[5];
    const float* br   = (const float*)d_in[6];
    const float* Wo   = (const float*)d_in[7];
    const float* bo   = (const float*)d_in[8];
    float* out = (float*)d_out;
    char* ws   = (char*)d_ws;

    float*          partials = (float*)(ws + WSB_PART);
    int*            ctr      = (int*)(ws + WSB_CTR);
    unsigned short* Wrt      = (unsigned short*)(ws + WSB_WRT);
    float*          ug       = (float*)(ws + WSB_U);
    float*          qg       = (float*)(ws + WSB_Q);
    unsigned short* W2t      = (unsigned short*)(ws + WSB_W2T);
    float*          C2g      = (float*)(ws + WSB_C2);
    unsigned short* Zg       = (unsigned short*)(ws + WSB_Z);

    k_prep<<<1, 256, 0, stream>>>(ln_w, ln_b, Wr, Wrt, ug, qg, ctr);
    k_pass1<<<dim3(32, B_), 256, 0, stream>>>(x, Wrt, ug, qg, ln_w, ln_b, Wl,
                                              bl, br, Wo, bo, partials, ctr,
                                              W2t, C2g, Zg);
    k_pass2<<<dim3(32, B_), 256, 0, stream>>>(Zg, W2t, C2g, out);
}